// Round 5
// baseline (281.075 us; speedup 1.0000x reference)
//
#include <hip/hip_runtime.h>

#define DIMB 2
#define DIMS 192
#define DPT 4        // d-outputs per thread
#define TX 16        // d-quads per block (64 d per block)
#define TY 16        // w rows per block
#define HCHUNK 6     // h rows per block

// Compute the 3x3 (w,d)-plane sums of the 5 product channels at row hh.
// d-window edges come from neighbor lanes via shuffle (lane = tx + 16*(ty&3),
// so lane+-1 is the d-neighbor for tx in [1,14]); block-boundary lanes use a
// 4-lane exec-masked scalar load (~4 cacheline requests vs 64 for a full
// strided scalar load — R1..R4 were TA/L1 request-throughput bound).
__device__ __forceinline__ void plane_sums(
    const float* __restrict__ pred, const float* __restrict__ targ,
    int b, int hh, int w, int tx, int d0, float (&P)[5][DPT])
{
#pragma unroll
    for (int c = 0; c < 5; ++c)
#pragma unroll
        for (int j = 0; j < DPT; ++j) P[c][j] = 0.f;
    if (hh < 0 || hh >= DIMS) return;   // hh is wave-uniform

    const bool lo_edge = (tx == 0);
    const bool hi_edge = (tx == TX - 1);

#pragma unroll
    for (int dw = -1; dw <= 1; ++dw) {
        const int wc = w + dw;
        const bool wok = (wc >= 0) & (wc < DIMS);
        const int base = ((b * DIMS + hh) * DIMS + (wok ? wc : 0)) * DIMS + d0;

        float4 mp = {0.f, 0.f, 0.f, 0.f}, mt = {0.f, 0.f, 0.f, 0.f};
        float lp = 0.f, lt = 0.f, hp = 0.f, ht = 0.f;
        if (wok) {
            mp = *reinterpret_cast<const float4*>(pred + base);
            mt = *reinterpret_cast<const float4*>(targ + base);
        }
        if (wok & lo_edge & (d0 > 0)) {             // 4 lanes/wave at most
            lp = pred[base - 1];  lt = targ[base - 1];
        }
        if (wok & hi_edge & (d0 + DPT < DIMS)) {    // 4 lanes/wave at most
            hp = pred[base + DPT]; ht = targ[base + DPT];
        }
        // all lanes reconverged: edges from neighbor lanes
        const float slp = __shfl_up(mp.w, 1, 64);
        const float slt = __shfl_up(mt.w, 1, 64);
        const float shp = __shfl_down(mp.x, 1, 64);
        const float sht = __shfl_down(mt.x, 1, 64);
        const float pv0 = lo_edge ? lp : slp;
        const float tv0 = lo_edge ? lt : slt;
        const float pv5 = hi_edge ? hp : shp;
        const float tv5 = hi_edge ? ht : sht;

        const float pv[6] = {pv0, mp.x, mp.y, mp.z, mp.w, pv5};
        const float tv[6] = {tv0, mt.x, mt.y, mt.z, mt.w, tv5};
        float pp[6], tt[6], pt[6];
#pragma unroll
        for (int k = 0; k < 6; ++k) {
            pp[k] = pv[k] * pv[k];
            tt[k] = tv[k] * tv[k];
            pt[k] = pv[k] * tv[k];
        }
#pragma unroll
        for (int j = 0; j < DPT; ++j) {
            P[0][j] += pv[j] + pv[j+1] + pv[j+2];
            P[1][j] += tv[j] + tv[j+1] + tv[j+2];
            P[2][j] += pp[j] + pp[j+1] + pp[j+2];
            P[3][j] += tt[j] + tt[j+1] + tt[j+2];
            P[4][j] += pt[j] + pt[j+1] + pt[j+2];
        }
    }
}

// One output row h: compute plane(h+1) into Pn, emit ncc for the DPT voxels.
__device__ __forceinline__ float do_row(
    const float* __restrict__ pred, const float* __restrict__ targ,
    int b, int h, int w, int tx, int d0,
    float (&Pm)[5][DPT], float (&Pc)[5][DPT], float (&Pn)[5][DPT])
{
    plane_sums(pred, targ, b, h + 1, w, tx, d0, Pn);
    const float inv = 1.0f / 27.0f;
    float acc = 0.f;
#pragma unroll
    for (int j = 0; j < DPT; ++j) {
        const float sI  = Pm[0][j] + Pc[0][j] + Pn[0][j];
        const float sJ  = Pm[1][j] + Pc[1][j] + Pn[1][j];
        const float sII = Pm[2][j] + Pc[2][j] + Pn[2][j];
        const float sJJ = Pm[3][j] + Pc[3][j] + Pn[3][j];
        const float sIJ = Pm[4][j] + Pc[4][j] + Pn[4][j];
        const float uI = sI * inv;
        const float uJ = sJ * inv;
        const float cross = sIJ - uI * sJ;
        const float pvar  = sII - uI * sI;
        const float tvar  = sJJ - uJ * sJ;
        acc += (cross * cross) * __builtin_amdgcn_rcpf(tvar * pvar + 1e-5f);
    }
    return acc;
}

__global__ __launch_bounds__(256)
void FusedLocalNormalizedCrossCorrelationLoss_37838661877790_kernel(
    const float* __restrict__ pred, const float* __restrict__ targ,
    double* __restrict__ acc_out)
{
    const int tx = threadIdx.x;                 // 16 d-quads
    const int ty = threadIdx.y;                 // 16 w rows
    const int d0 = (blockIdx.x * TX + tx) * DPT;
    const int w  = blockIdx.y * TY + ty;
    const int bz = blockIdx.z;
    const int b  = bz >> 5;                     // 2 batches
    const int h0 = (bz & 31) * HCHUNK;          // 32 h-chunks

    float P[3][5][DPT];
    plane_sums(pred, targ, b, h0 - 1, w, tx, d0, P[0]);
    plane_sums(pred, targ, b, h0,     w, tx, d0, P[1]);

    float acc = 0.f;
    // 3-phase role rotation (compile-time indices only — no copies, no
    // dynamic indexing that could demote arrays to scratch).
#pragma unroll
    for (int hb = 0; hb < HCHUNK; hb += 3) {
        acc += do_row(pred, targ, b, h0 + hb,     w, tx, d0, P[0], P[1], P[2]);
        acc += do_row(pred, targ, b, h0 + hb + 1, w, tx, d0, P[1], P[2], P[0]);
        acc += do_row(pred, targ, b, h0 + hb + 2, w, tx, d0, P[2], P[0], P[1]);
    }

    // Reduction: wave shuffle tree -> LDS -> one fp64 atomic per block.
#pragma unroll
    for (int off = 32; off > 0; off >>= 1)
        acc += __shfl_down(acc, off, 64);
    __shared__ float wacc[4];
    const int tid = ty * TX + tx;
    if ((tid & 63) == 0) wacc[tid >> 6] = acc;
    __syncthreads();
    if (tid == 0) {
        const double s = (double)wacc[0] + (double)wacc[1]
                       + (double)wacc[2] + (double)wacc[3];
        atomicAdd(acc_out, s);
    }
}

__global__ void ncc_finalize(const double* __restrict__ acc,
                             float* __restrict__ out)
{
    const double n = (double)((size_t)DIMB * DIMS * DIMS * DIMS);
    out[0] = (float)(-acc[0] / n);
}

extern "C" void kernel_launch(void* const* d_in, const int* in_sizes, int n_in,
                              void* d_out, int out_size, void* d_ws, size_t ws_size,
                              hipStream_t stream) {
    const float* pred = (const float*)d_in[0];
    const float* targ = (const float*)d_in[1];
    double* acc = (double*)d_ws;

    hipMemsetAsync(d_ws, 0, sizeof(double), stream);

    dim3 block(TX, TY, 1);
    dim3 grid(DIMS / (TX * DPT), DIMS / TY, DIMB * (DIMS / HCHUNK)); // 3 x 12 x 64
    FusedLocalNormalizedCrossCorrelationLoss_37838661877790_kernel
        <<<grid, block, 0, stream>>>(pred, targ, acc);
    ncc_finalize<<<1, 1, 0, stream>>>(acc, (float*)d_out);
}

// Round 6
// 177.452 us; speedup vs baseline: 1.5840x; 1.5840x over previous
//
#include <hip/hip_runtime.h>

#define DIMB 2
#define DIMS 192
#define DPT 4          // d-outputs per thread
#define TX 16          // d-quads per block (64 d per block)
#define TY 16          // w rows per block
#define HCHUNK 6       // output h rows per block
#define ROWF 72        // floats per staged row (d0b-4 .. d0b+67)
#define PLANE_F 1296   // 18 rows * 72 floats per array
#define BUF_F 2816     // 11 segments * 256 floats (padded)
#define NSEG 11        // ceil(2*PLANE_F / 256)

// Async global->LDS staging: each wave instruction stages 64 lanes x 16 B = 1 KB
// into LDS at wave-uniform base + lane*16 (m104 contract). Prefetch lives in
// LDS, not VGPRs -- R3/R4 register pipelines spilled (99-443 MB scratch).
#define GLOAD_LDS16(gp, lp) __builtin_amdgcn_global_load_lds( \
    (const __attribute__((address_space(1))) void*)(gp),      \
    (__attribute__((address_space(3))) void*)(lp), 16, 0, 0)

__device__ __forceinline__ float ncc_row3(const float (&Pm)[5][DPT],
                                          const float (&Pc)[5][DPT],
                                          const float (&Pn)[5][DPT])
{
    const float inv = 1.0f / 27.0f;
    float acc = 0.f;
#pragma unroll
    for (int j = 0; j < DPT; ++j) {
        const float sI  = Pm[0][j] + Pc[0][j] + Pn[0][j];
        const float sJ  = Pm[1][j] + Pc[1][j] + Pn[1][j];
        const float sII = Pm[2][j] + Pc[2][j] + Pn[2][j];
        const float sJJ = Pm[3][j] + Pc[3][j] + Pn[3][j];
        const float sIJ = Pm[4][j] + Pc[4][j] + Pn[4][j];
        const float uI = sI * inv;
        const float uJ = sJ * inv;
        const float cross = sIJ - uI * sJ;
        const float pvar  = sII - uI * sI;
        const float tvar  = sJJ - uJ * sJ;
        acc += (cross * cross) * __builtin_amdgcn_rcpf(tvar * pvar + 1e-5f);
    }
    return acc;
}

__global__ __launch_bounds__(256)
void FusedLocalNormalizedCrossCorrelationLoss_37838661877790_kernel(
    const float* __restrict__ pred, const float* __restrict__ targ,
    double* __restrict__ acc_out)
{
    __shared__ float L[2][BUF_F];    // double-buffered plane pair (22.5 KB)

    const int tx = threadIdx.x, ty = threadIdx.y;
    const int tid = ty * TX + tx;
    const int lane = tid & 63, wv = tid >> 6;
    const int d0b = blockIdx.x * (TX * DPT);     // 0, 64, 128
    const int w0  = blockIdx.y * TY;
    const int bz  = blockIdx.z;
    const int b   = bz >> 5;                     // 2 batches
    const int h0  = (bz & 31) * HCHUNK;          // 32 h-chunks

    // ---- per-thread stage-segment precompute (plane-invariant) ----
    // Segment s (0..10) = 256 floats of the plane-pair; wave wv handles
    // s = wv, wv+4, wv+8. Lane covers floats s*256 + lane*4 .. +3.
    int   sl[3]; int co[3]; const float* ab[3];
#pragma unroll
    for (int i = 0; i < 3; ++i) {
        const int s = wv + 4 * i;
        const int ss = (s < NSEG) ? s : 0;       // wave 3 has 2 segments
        const int fi = ss * 256 + lane * 4;
        const int a  = (fi >= PLANE_F) ? 1 : 0;
        int fi2 = fi - a * PLANE_F;
        if (fi2 > PLANE_F - 1) fi2 = PLANE_F - 1;   // LDS pad region
        const int r = fi2 / ROWF, c = fi2 % ROWF;
        int gd = d0b - 4 + c;                    // multiple of 4 -> 16B aligned
        gd = gd < 0 ? 0 : (gd > DIMS - 4 ? DIMS - 4 : gd);
        int wr = w0 - 1 + r;
        wr = wr < 0 ? 0 : (wr > DIMS - 1 ? DIMS - 1 : wr);
        sl[i] = ss * 256;                        // wave-uniform LDS float base
        co[i] = wr * DIMS + gd;                  // clamped; garbage masked later
        ab[i] = a ? targ : pred;
    }

    auto stage = [&](int buf, int hh) {
        const int hhc = hh < 0 ? 0 : (hh > DIMS - 1 ? DIMS - 1 : hh);
        const size_t po = ((size_t)b * DIMS + hhc) * (DIMS * DIMS);
#pragma unroll
        for (int i = 0; i < 3; ++i) {
            if (wv + 4 * i >= NSEG) break;       // wave-uniform
            GLOAD_LDS16(ab[i] + po + co[i], &L[buf][sl[i]]);
        }
    };

    // d-edge masks: window ends refer to gd = d0b-1 / d0b+64, invalid only at
    // the global d boundaries (clamped loads put garbage there).
    const bool lo_mask = (tx == 0)      && (blockIdx.x == 0);
    const bool hi_mask = (tx == TX - 1) && (blockIdx.x == gridDim.x - 1);
    const int rb0 = 4 * tx;

    auto plane = [&](int buf, int hh, float (&P)[5][DPT]) {
#pragma unroll
        for (int c5 = 0; c5 < 5; ++c5)
#pragma unroll
            for (int j = 0; j < DPT; ++j) P[c5][j] = 0.f;
        if (hh < 0 || hh >= DIMS) return;        // uniform per block
        const float* Lp = &L[buf][0];
        const float* Lt = &L[buf][PLANE_F];
#pragma unroll
        for (int dw = 0; dw < 3; ++dw) {
            const int wr = w0 + ty + dw - 1;
            if (wr < 0 || wr >= DIMS) continue;  // garbage halo row
            const int rb = (ty + dw) * ROWF + rb0;
            float p0 = Lp[rb + 3];
            const float4 pm = *reinterpret_cast<const float4*>(Lp + rb + 4);
            float p5 = Lp[rb + 8];
            float t0 = Lt[rb + 3];
            const float4 tm = *reinterpret_cast<const float4*>(Lt + rb + 4);
            float t5 = Lt[rb + 8];
            if (lo_mask) { p0 = 0.f; t0 = 0.f; }
            if (hi_mask) { p5 = 0.f; t5 = 0.f; }
            const float pv[6] = {p0, pm.x, pm.y, pm.z, pm.w, p5};
            const float tv[6] = {t0, tm.x, tm.y, tm.z, tm.w, t5};
            float pp[6], tt[6], pt[6];
#pragma unroll
            for (int k = 0; k < 6; ++k) {
                pp[k] = pv[k] * pv[k];
                tt[k] = tv[k] * tv[k];
                pt[k] = pv[k] * tv[k];
            }
#pragma unroll
            for (int j = 0; j < DPT; ++j) {
                P[0][j] += pv[j] + pv[j+1] + pv[j+2];
                P[1][j] += tv[j] + tv[j+1] + tv[j+2];
                P[2][j] += pp[j] + pp[j+1] + pp[j+2];
                P[3][j] += tt[j] + tt[j+1] + tt[j+2];
                P[4][j] += pt[j] + pt[j+1] + pt[j+2];
            }
        }
    };

    // Plane q (hh = h0-1+q) lives in buffer q&1; 1 barrier per plane.
    // stage(X, q+2) issued right before consuming plane q+1 -> one full
    // plane-compute of latency cover before the barrier drain needs it.
    float PA[5][DPT], PB[5][DPT], PC[5][DPT];
    float acc = 0.f;

    stage(0, h0 - 1);
    stage(1, h0);
    __syncthreads();                       // q0,q1 ready
    plane(0, h0 - 1, PA);
    __syncthreads();                       // all reads of buf0 done
    stage(0, h0 + 1);
    plane(1, h0, PB);
    __syncthreads();
    stage(1, h0 + 2);
    plane(0, h0 + 1, PC);  acc += ncc_row3(PA, PB, PC);
    __syncthreads();
    stage(0, h0 + 3);
    plane(1, h0 + 2, PA);  acc += ncc_row3(PB, PC, PA);
    __syncthreads();
    stage(1, h0 + 4);
    plane(0, h0 + 3, PB);  acc += ncc_row3(PC, PA, PB);
    __syncthreads();
    stage(0, h0 + 5);
    plane(1, h0 + 4, PC);  acc += ncc_row3(PA, PB, PC);
    __syncthreads();
    stage(1, h0 + 6);
    plane(0, h0 + 5, PA);  acc += ncc_row3(PB, PC, PA);
    __syncthreads();
    plane(1, h0 + 6, PB);  acc += ncc_row3(PC, PA, PB);

    // Reduction: wave shuffle tree -> LDS -> one fp64 atomic per block.
#pragma unroll
    for (int off = 32; off > 0; off >>= 1)
        acc += __shfl_down(acc, off, 64);
    __shared__ float wacc[4];
    if ((tid & 63) == 0) wacc[tid >> 6] = acc;
    __syncthreads();
    if (tid == 0) {
        const double s = (double)wacc[0] + (double)wacc[1]
                       + (double)wacc[2] + (double)wacc[3];
        atomicAdd(acc_out, s);
    }
}

__global__ void ncc_finalize(const double* __restrict__ acc,
                             float* __restrict__ out)
{
    const double n = (double)((size_t)DIMB * DIMS * DIMS * DIMS);
    out[0] = (float)(-acc[0] / n);
}

extern "C" void kernel_launch(void* const* d_in, const int* in_sizes, int n_in,
                              void* d_out, int out_size, void* d_ws, size_t ws_size,
                              hipStream_t stream) {
    const float* pred = (const float*)d_in[0];
    const float* targ = (const float*)d_in[1];
    double* acc = (double*)d_ws;

    hipMemsetAsync(d_ws, 0, sizeof(double), stream);

    dim3 block(TX, TY, 1);
    dim3 grid(DIMS / (TX * DPT), DIMS / TY, DIMB * (DIMS / HCHUNK)); // 3 x 12 x 64
    FusedLocalNormalizedCrossCorrelationLoss_37838661877790_kernel
        <<<grid, block, 0, stream>>>(pred, targ, acc);
    ncc_finalize<<<1, 1, 0, stream>>>(acc, (float*)d_out);
}